// Round 6
// baseline (545.144 us; speedup 1.0000x reference)
//
#include <hip/hip_runtime.h>
#include <stdint.h>

#define DEV static __device__ __forceinline__

typedef __attribute__((ext_vector_type(8))) short bf16x8;
typedef __attribute__((ext_vector_type(4))) float f32x4;

constexpr int Bc = 8, Tc = 2048, Cc = 1024, Hc = 16, Dc = 64;

DEV ushort f2bf(float f) {
  union { float f; uint32_t u; } x{f};
  uint32_t r = (x.u + 0x7FFFu + ((x.u >> 16) & 1u)) >> 16;
  return (ushort)r;
}

DEV uint32_t cvt_pk_bf16(float a, float b) {
  uint32_t r;
  asm("v_cvt_pk_bf16_f32 %0, %1, %2" : "=v"(r) : "v"(a), "v"(b));
  return r;
}

DEV float max3f(float a, float b, float c) {
  float r;
  asm("v_max3_f32 %0, %1, %2, %3" : "=v"(r) : "v"(a), "v"(b), "v"(c));
  return r;
}

DEV void gload16(const ushort* g, ushort* l) {
  __builtin_amdgcn_global_load_lds(
      (const __attribute__((address_space(1))) unsigned int*)g,
      (__attribute__((address_space(3))) unsigned int*)l, 16, 0, 0);
}

DEV f32x4 mfma16(bf16x8 a, bf16x8 b, f32x4 c) {
  return __builtin_amdgcn_mfma_f32_16x16x32_bf16(a, b, c, 0, 0, 0);
}

union B8 { bf16x8 v; uint4 u; };

// counted-vmcnt primitives
DEV void vm4() { asm volatile("s_waitcnt vmcnt(4)" ::: "memory"); }
DEV void vm0() { asm volatile("s_waitcnt vmcnt(0)" ::: "memory"); }
DEV void memfence() { asm volatile("" ::: "memory"); }
DEV void pbar() {
  __builtin_amdgcn_sched_barrier(0);
  __builtin_amdgcn_s_barrier();
  __builtin_amdgcn_sched_barrier(0);
}

// ---------------- converts ----------------
__global__ __launch_bounds__(256) void k_conv_x(const float* __restrict__ x, ushort* __restrict__ xb) {
  int i = blockIdx.x * 256 + threadIdx.x;
  float4 v = ((const float4*)x)[i];
  ushort4 o = make_ushort4(f2bf(v.x), f2bf(v.y), f2bf(v.z), f2bf(v.w));
  ((ushort4*)xb)[i] = o;
}

__global__ __launch_bounds__(256) void k_conv_wqkv(const float* __restrict__ wq, const float* __restrict__ wk,
                                                   const float* __restrict__ wv, ushort* __restrict__ wt) {
  int i = blockIdx.x * 256 + threadIdx.x;   // 0 .. 3072*1024-1
  int c = i & 1023;
  int n = i >> 10;
  int which = n >> 10;
  int rem = n & 1023;
  int h = rem >> 6, d = rem & 63;
  const float* src = which == 0 ? wq : (which == 1 ? wk : wv);
  float v = src[((size_t)h * 1024 + c) * 64 + d];
  // fold C^-0.5 = 1/32 AND log2(e) (for exp2-softmax) into wq
  if (which == 0) v *= 0.03125f * 1.44269504088896340736f;
  wt[i] = f2bf(v);
}

__global__ __launch_bounds__(256) void k_conv_wproj(const float* __restrict__ wp, ushort* __restrict__ wt) {
  int i = blockIdx.x * 256 + threadIdx.x;   // 0 .. 1024*1024-1
  int n = i >> 10, k = i & 1023;
  wt[i] = f2bf(wp[(size_t)k * 1024 + n]);
}

// ---------------- 256x256 8-wave counted-vmcnt GEMM mainloop (K=1024, BK=64) ----------------
// 2 K-tile LDS buffers (128 KB). Per K-tile: 4 phases x 16 MFMA; 2 fences (vmcnt(4)+barrier).
// Order-immune ledger: R1 (P1) issues {Aq0,Bq0}(t+1); R2 (P2-P4) issues {Aq1,Bq1}(t+1).
// F1 (P1-end, vmcnt(4)) -> {Aq1,Bq1}(t) landed for P2/P3; F4 (P4-end, vmcnt(4)) ->
// {Aq0,Bq0}(t+1) landed for next P1. Quarters: A by row bit6 (phase m-half),
// B by row bit5 (nf 0-1 vs 2-3). LDS swizzle (row&7)<<4 via pre-swizzled global source.
DEV void gemm256_main(const ushort* __restrict__ A, const ushort* __restrict__ B,
                      int m0, int n0, int tid, ushort* ldsA, ushort* ldsB,
                      f32x4 (&acc)[8][4]) {
  const int lane = tid & 63;
  const int lr = lane & 15, lg = lane >> 4;
  const int wid = tid >> 6;
  const int wm = wid >> 2, wn = wid & 3;
  constexpr int NT = 16;

  auto stageA = [&](int q, int t) {
#pragma unroll
    for (int j = 0; j < 2; ++j) {
      int c = tid + q * 512 + j * 1024;
      int row = c >> 3;
      int col = 8 * ((c & 7) ^ (row & 7));
      gload16(&A[(size_t)(m0 + row) * 1024 + t * 64 + col], &ldsA[(t & 1) * 16384 + c * 8]);
    }
  };
  auto stageB = [&](int q, int t) {
#pragma unroll
    for (int j = 0; j < 2; ++j) {
      int c = q * 256 + (tid & 255) + ((tid >> 8) + 2 * j) * 512;
      int row = c >> 3;
      int col = 8 * ((c & 7) ^ (row & 7));
      gload16(&B[(size_t)(n0 + row) * 1024 + t * 64 + col], &ldsB[(t & 1) * 16384 + c * 8]);
    }
  };
  auto rdA = [&](bf16x8 (&af)[2][4], const ushort* bA, int mh) {
#pragma unroll
    for (int kc = 0; kc < 2; ++kc)
#pragma unroll
      for (int mf = 0; mf < 4; ++mf) {
        int row = wm * 128 + mh * 64 + mf * 16 + lr;
        af[kc][mf] = *(const bf16x8*)((const char*)bA + row * 128 + ((kc * 64 + lg * 16) ^ ((row & 7) << 4)));
      }
  };
  auto rdB = [&](bf16x8 (&bf)[2][2], const ushort* bB, int nh) {
#pragma unroll
    for (int kc = 0; kc < 2; ++kc)
#pragma unroll
      for (int nf = 0; nf < 2; ++nf) {
        int row = wn * 64 + nh * 32 + nf * 16 + lr;
        bf[kc][nf] = *(const bf16x8*)((const char*)bB + row * 128 + ((kc * 64 + lg * 16) ^ ((row & 7) << 4)));
      }
  };

  // prologue: tile 0, fence-separated quarter order [Aq0,Bq0 | Aq1,Bq1]
  stageA(0, 0); stageB(0, 0);
  memfence();
  stageA(1, 0); stageB(1, 0);
  vm4();
  pbar();

  for (int t = 0; t < NT; ++t) {
    const ushort* bA = ldsA + (t & 1) * 16384;
    const ushort* bB = ldsB + (t & 1) * 16384;
    const bool pf = (t + 1) < NT;
    bf16x8 af[2][4], bf0[2][2], bf1[2][2];
    // ---- P1: reads Aq0(t)+Bq0(t); issues Aq0,Bq0(t+1)
    if (pf) { stageA(0, t + 1); stageB(0, t + 1); }
    rdA(af, bA, 0);
    rdB(bf0, bB, 0);
    __builtin_amdgcn_s_setprio(1);
#pragma unroll
    for (int kc = 0; kc < 2; ++kc)
#pragma unroll
      for (int mf = 0; mf < 4; ++mf)
#pragma unroll
        for (int nf = 0; nf < 2; ++nf)
          acc[mf][nf] = mfma16(af[kc][mf], bf0[kc][nf], acc[mf][nf]);
    __builtin_amdgcn_s_setprio(0);
    if (pf) vm4(); else vm0();   // F1: {Aq1,Bq1}(t) landed
    pbar();
    // ---- P2: reads Bq1(t); issues Aq1(t+1)
    if (pf) stageA(1, t + 1);
    rdB(bf1, bB, 1);
    __builtin_amdgcn_s_setprio(1);
#pragma unroll
    for (int kc = 0; kc < 2; ++kc)
#pragma unroll
      for (int mf = 0; mf < 4; ++mf)
#pragma unroll
        for (int nf = 0; nf < 2; ++nf)
          acc[mf][2 + nf] = mfma16(af[kc][mf], bf1[kc][nf], acc[mf][2 + nf]);
    __builtin_amdgcn_s_setprio(0);
    // ---- P3: reads Aq1(t); issues Bq1(t+1)
    if (pf) stageB(1, t + 1);
    rdA(af, bA, 1);
    __builtin_amdgcn_s_setprio(1);
#pragma unroll
    for (int kc = 0; kc < 2; ++kc)
#pragma unroll
      for (int mf = 0; mf < 4; ++mf)
#pragma unroll
        for (int nf = 0; nf < 2; ++nf)
          acc[4 + mf][nf] = mfma16(af[kc][mf], bf0[kc][nf], acc[4 + mf][nf]);
    __builtin_amdgcn_s_setprio(0);
    // ---- P4 (no new ds_reads)
    __builtin_amdgcn_s_setprio(1);
#pragma unroll
    for (int kc = 0; kc < 2; ++kc)
#pragma unroll
      for (int mf = 0; mf < 4; ++mf)
#pragma unroll
        for (int nf = 0; nf < 2; ++nf)
          acc[4 + mf][2 + nf] = mfma16(af[kc][mf], bf1[kc][nf], acc[4 + mf][2 + nf]);
    __builtin_amdgcn_s_setprio(0);
    if (pf) vm4(); else vm0();   // F4: {Aq0,Bq0}(t+1) landed
    pbar();
  }
}

// ---------------- QKV projection GEMM (256^2) ----------------
__global__ __launch_bounds__(512, 2) void k_gemm_qkv(const ushort* __restrict__ xb, const ushort* __restrict__ wt,
                                                     ushort* __restrict__ qws, ushort* __restrict__ kws,
                                                     ushort* __restrict__ vws) {
  __shared__ __align__(16) ushort ldsA[2 * 16384];
  __shared__ __align__(16) ushort ldsB[2 * 16384];
  const int tid = threadIdx.x;
  const int orig = blockIdx.x;                 // 768 blocks
  const int wgid = (orig & 7) * 96 + (orig >> 3);  // bijective XCD swizzle (768 % 8 == 0)
  const int bn = wgid >> 6, bm = wgid & 63;    // consecutive wgid share B panel
  const int m0 = bm * 256, n0 = bn * 256;
  f32x4 acc[8][4];
  f32x4 z = {0.f, 0.f, 0.f, 0.f};
#pragma unroll
  for (int i = 0; i < 8; ++i)
#pragma unroll
    for (int j = 0; j < 4; ++j) acc[i][j] = z;
  gemm256_main(xb, wt, m0, n0, tid, ldsA, ldsB, acc);
  const int lane = tid & 63, wid = tid >> 6;
  const int lr = lane & 15, lg = lane >> 4;
  const int wm = wid >> 2, wn = wid & 3;
#pragma unroll
  for (int a = 0; a < 8; ++a)
#pragma unroll
    for (int nf = 0; nf < 4; ++nf)
#pragma unroll
      for (int r = 0; r < 4; ++r) {
        int m = m0 + wm * 128 + (a >> 2) * 64 + (a & 3) * 16 + lg * 4 + r;
        int n = n0 + wn * 64 + nf * 16 + lr;
        int which = n >> 10, rem = n & 1023;
        int h = rem >> 6, d = rem & 63;
        int b = m >> 11, t = m & 2047;
        ushort* dst = which == 0 ? qws : (which == 1 ? kws : vws);
        dst[((size_t)(b * Hc + h) * Tc + t) * 64 + d] = f2bf(acc[a][nf][r]);
      }
}

// ---------------- output projection GEMM (256^2, +bias, fp32 out) ----------------
__global__ __launch_bounds__(512, 2) void k_gemm_proj(const ushort* __restrict__ attb, const ushort* __restrict__ wt,
                                                      const float* __restrict__ bias, float* __restrict__ out) {
  __shared__ __align__(16) ushort ldsA[2 * 16384];
  __shared__ __align__(16) ushort ldsB[2 * 16384];
  const int tid = threadIdx.x;
  const int orig = blockIdx.x;                 // 256 blocks
  const int wgid = (orig & 7) * 32 + (orig >> 3);  // bijective XCD swizzle (256 % 8 == 0)
  const int bn = wgid >> 6, bm = wgid & 63;
  const int m0 = bm * 256, n0 = bn * 256;
  f32x4 acc[8][4];
  f32x4 z = {0.f, 0.f, 0.f, 0.f};
#pragma unroll
  for (int i = 0; i < 8; ++i)
#pragma unroll
    for (int j = 0; j < 4; ++j) acc[i][j] = z;
  gemm256_main(attb, wt, m0, n0, tid, ldsA, ldsB, acc);
  const int lane = tid & 63, wid = tid >> 6;
  const int lr = lane & 15, lg = lane >> 4;
  const int wm = wid >> 2, wn = wid & 3;
#pragma unroll
  for (int a = 0; a < 8; ++a)
#pragma unroll
    for (int nf = 0; nf < 4; ++nf)
#pragma unroll
      for (int r = 0; r < 4; ++r) {
        int m = m0 + wm * 128 + (a >> 2) * 64 + (a & 3) * 16 + lg * 4 + r;
        int n = n0 + wn * 64 + nf * 16 + lr;
        out[(size_t)m * 1024 + n] = acc[a][nf][r] + bias[n];
      }
}

// ---------------- V transpose: (B,H,T,D) -> (B,H,D,T) ----------------
__global__ __launch_bounds__(256) void k_vtrans(const ushort* __restrict__ v, ushort* __restrict__ vt) {
  __shared__ ushort lds[64][68];
  const int t0 = blockIdx.x * 64;
  const int bh = blockIdx.y;
  const int tid = threadIdx.x;
  const ushort* src = v + (size_t)bh * Tc * 64;
  ushort* dst = vt + (size_t)bh * 64 * Tc;
#pragma unroll
  for (int j = 0; j < 4; ++j) {
    int flat = j * 256 + tid;
    int row = flat >> 4, cg = flat & 15;
    ushort4 x = *(const ushort4*)&src[(size_t)(t0 + row) * 64 + cg * 4];
    lds[row][cg * 4 + 0] = x.x; lds[row][cg * 4 + 1] = x.y;
    lds[row][cg * 4 + 2] = x.z; lds[row][cg * 4 + 3] = x.w;
  }
  __syncthreads();
#pragma unroll
  for (int j = 0; j < 4; ++j) {
    int flat = j * 256 + tid;
    int d = flat >> 4, tg = flat & 15;
    ushort4 x = make_ushort4(lds[tg * 4 + 0][d], lds[tg * 4 + 1][d], lds[tg * 4 + 2][d], lds[tg * 4 + 3][d]);
    *(ushort4*)&dst[(size_t)d * Tc + t0 + tg * 4] = x;
  }
}

// ---------------- flash attention (causal) — UNCHANGED from round 5 ----------------
DEV int swzK(int row, int bcol) { return row * 128 + (bcol ^ ((row & 7) << 4)); }  // 128B pitch
DEV int swzV(int row, int bcol) { return row * 256 + (bcol ^ ((row & 7) << 4)); }  // 256B pitch

__global__ __launch_bounds__(256) void k_attn(const ushort* __restrict__ qws, const ushort* __restrict__ kws,
                                              const ushort* __restrict__ vtws, ushort* __restrict__ att) {
  const int id = blockIdx.x;
  const int xcd = id & 7, slot = id >> 3;
  const int bh = (xcd << 4) + (slot >> 3);   // 16 bh per XCD, same-bh blocks adjacent
  const int qi = slot & 7;                    // 0..7
  const int tid = threadIdx.x, lane = tid & 63, wid = tid >> 6;
  const int lr = lane & 15, lg = lane >> 4;

  __shared__ __align__(16) ushort lds_k[2 * 128 * 64];  // K: 128 s-rows x 64 d (128B pitch)
  __shared__ __align__(16) ushort lds_v[2 * 64 * 128];  // V^T: 64 d-rows x 128 s (256B pitch)

  const ushort* qbase = qws + (size_t)bh * Tc * 64;
  const ushort* kbase = kws + (size_t)bh * Tc * 64;
  const ushort* vtbase = vtws + (size_t)bh * 64 * Tc;
  const int b = bh >> 4, h = bh & 15;
  const f32x4 z = {0.f, 0.f, 0.f, 0.f};

  int rowK[4], colK[4], rowV[4], colV[4];
#pragma unroll
  for (int r = 0; r < 4; ++r) {
    int c = r * 256 + tid;
    rowK[r] = c >> 3; colK[r] = 8 * ((c & 7) ^ (rowK[r] & 7));
    rowV[r] = c >> 4; colV[r] = 8 * ((c & 15) ^ (rowV[r] & 7));
  }

  B8 onesf;
  {
    uint32_t pp = lr == 0 ? 0x3F803F80u : 0u;
    onesf.u = make_uint4(pp, pp, pp, pp);
  }

  for (int pass = 0; pass < 2; ++pass) {
    const int qb = pass == 0 ? qi : 15 - qi;
    const int q0 = qb * 128;
    const int ntiles = qb + 1;          // KVBLK=128
    const int qrow = q0 + wid * 32;
    const int qgmax = qrow + 31;

    bf16x8 qa[2][2];
#pragma unroll
    for (int qf = 0; qf < 2; ++qf)
#pragma unroll
      for (int kc = 0; kc < 2; ++kc)
        qa[qf][kc] = *(const bf16x8*)&qbase[(size_t)(qrow + qf * 16 + lr) * 64 + kc * 32 + lg * 8];

    f32x4 o[2][4];
    f32x4 lac[2];
    float m_[2];
#pragma unroll
    for (int qf = 0; qf < 2; ++qf) {
#pragma unroll
      for (int df = 0; df < 4; ++df) o[qf][df] = z;
      lac[qf] = z;
      m_[qf] = -1e30f;
    }

    __syncthreads();  // previous pass's readers done before restaging buf 0

#pragma unroll
    for (int r = 0; r < 4; ++r) {
      gload16(&kbase[(size_t)rowK[r] * 64 + colK[r]], &lds_k[(r * 256 + tid) * 8]);
      gload16(&vtbase[(size_t)rowV[r] * Tc + colV[r]], &lds_v[(r * 256 + tid) * 8]);
    }

    for (int it = 0; it < ntiles; ++it) {
      __syncthreads();
      const ushort* ldsK = lds_k + (it & 1) * 8192;
      const ushort* ldsV = lds_v + (it & 1) * 8192;
      if (it + 1 < ntiles) {
        const int s0n = (it + 1) * 128;
        ushort* dK = lds_k + ((it + 1) & 1) * 8192;
        ushort* dV = lds_v + ((it + 1) & 1) * 8192;
#pragma unroll
        for (int r = 0; r < 4; ++r) {
          gload16(&kbase[(size_t)(s0n + rowK[r]) * 64 + colK[r]], &dK[(r * 256 + tid) * 8]);
          gload16(&vtbase[(size_t)rowV[r] * Tc + s0n + colV[r]], &dV[(r * 256 + tid) * 8]);
        }
      }

      const int s0 = it * 128;
      const bool diag = (it == ntiles - 1);
      const int nlive = diag ? 2 * wid + 2 : 8;

      f32x4 s[8][2];
#pragma unroll
      for (int sf = 0; sf < 8; ++sf)
#pragma unroll
        for (int qf = 0; qf < 2; ++qf) s[sf][qf] = z;
#pragma unroll
      for (int kc = 0; kc < 2; ++kc) {
        bf16x8 kf[8];
#pragma unroll
        for (int sf = 0; sf < 8; ++sf)
          if (sf < nlive)
            kf[sf] = *(const bf16x8*)((const char*)ldsK + swzK(sf * 16 + lr, kc * 64 + lg * 16));
        __builtin_amdgcn_s_setprio(1);
#pragma unroll
        for (int sf = 0; sf < 8; ++sf)
          if (sf < nlive)
#pragma unroll
            for (int qf = 0; qf < 2; ++qf)
              s[sf][qf] = mfma16(kf[sf], qa[qf][kc], s[sf][qf]);
        __builtin_amdgcn_s_setprio(0);
      }

      if (diag) {
#pragma unroll
        for (int sf = 0; sf < 8; ++sf)
#pragma unroll
          for (int qf = 0; qf < 2; ++qf)
#pragma unroll
            for (int r = 0; r < 4; ++r) {
              int sg = s0 + sf * 16 + lg * 4 + r;
              int qg = qrow + qf * 16 + lr;
              if (sg > qg) s[sf][qf][r] = -1e30f;
            }
      }

      float sc[2];
      bool defer[2];
#pragma unroll
      for (int qf = 0; qf < 2; ++qf) {
        float rs[8];
#pragma unroll
        for (int sf = 0; sf < 8; ++sf)
          rs[sf] = fmaxf(max3f(s[sf][qf][0], s[sf][qf][1], s[sf][qf][2]), s[sf][qf][3]);
        float t = max3f(max3f(rs[0], rs[1], rs[2]), max3f(rs[3], rs[4], rs[5]), fmaxf(rs[6], rs[7]));
        t = fmaxf(t, __shfl_xor(t, 16));
        t = fmaxf(t, __shfl_xor(t, 32));
        defer[qf] = __all(t <= m_[qf] + 11.54f) != 0;
        float mnew = defer[qf] ? m_[qf] : fmaxf(m_[qf], t);
        sc[qf] = defer[qf] ? 1.f : exp2f(m_[qf] - mnew);
        m_[qf] = mnew;
#pragma unroll
        for (int sf = 0; sf < 8; ++sf)
#pragma unroll
          for (int r = 0; r < 4; ++r)
            s[sf][qf][r] = exp2f(s[sf][qf][r] - mnew);
      }
#pragma unroll
      for (int qf = 0; qf < 2; ++qf)
        if (!defer[qf]) {
#pragma unroll
          for (int r = 0; r < 4; ++r) {
            float scR = __shfl(sc[qf], ((lane >> 4) << 2) + r);
#pragma unroll
            for (int df = 0; df < 4; ++df) o[qf][df][r] *= scR;
            lac[qf][r] *= scR;
          }
        }

      uint32_t pk_[8][2][2];
#pragma unroll
      for (int sf = 0; sf < 8; ++sf)
#pragma unroll
        for (int qf = 0; qf < 2; ++qf) {
          pk_[sf][qf][0] = cvt_pk_bf16(s[sf][qf][0], s[sf][qf][1]);
          pk_[sf][qf][1] = cvt_pk_bf16(s[sf][qf][2], s[sf][qf][3]);
        }

#pragma unroll
      for (int kc = 0; kc < 4; ++kc) {
        B8 vf[4];
#pragma unroll
        for (int df = 0; df < 4; ++df) {
          uint2 lo = *(const uint2*)((const char*)ldsV + swzV(df * 16 + lr, kc * 64 + lg * 8));
          uint2 hi = *(const uint2*)((const char*)ldsV + swzV(df * 16 + lr, kc * 64 + 32 + lg * 8));
          vf[df].u = make_uint4(lo.x, lo.y, hi.x, hi.y);
        }
        B8 pf[2];
#pragma unroll
        for (int qf = 0; qf < 2; ++qf)
          pf[qf].u = make_uint4(pk_[2 * kc][qf][0], pk_[2 * kc][qf][1],
                                pk_[2 * kc + 1][qf][0], pk_[2 * kc + 1][qf][1]);
        __builtin_amdgcn_s_setprio(1);
#pragma unroll
        for (int qf = 0; qf < 2; ++qf) {
#pragma unroll
          for (int df = 0; df < 4; ++df)
            o[qf][df] = mfma16(pf[qf].v, vf[df].v, o[qf][df]);
          lac[qf] = mfma16(pf[qf].v, onesf.v, lac[qf]);
        }
        __builtin_amdgcn_s_setprio(0);
      }
    }

#pragma unroll
    for (int qf = 0; qf < 2; ++qf)
#pragma unroll
      for (int r = 0; r < 4; ++r) {
        float lR = __shfl(lac[qf][r], lg << 4);
        float inv = 1.f / lR;
        int qg = qrow + qf * 16 + lg * 4 + r;
#pragma unroll
        for (int df = 0; df < 4; ++df) {
          int d = df * 16 + lr;
          att[(size_t)(b * Tc + qg) * 1024 + h * 64 + d] = f2bf(o[qf][df][r] * inv);
        }
      }
  }
}

extern "C" void kernel_launch(void* const* d_in, const int* in_sizes, int n_in,
                              void* d_out, int out_size, void* d_ws, size_t ws_size,
                              hipStream_t stream) {
  const float* x  = (const float*)d_in[0];
  const float* wq = (const float*)d_in[1];
  const float* wk = (const float*)d_in[2];
  const float* wv = (const float*)d_in[3];
  const float* wp = (const float*)d_in[4];
  const float* bp = (const float*)d_in[5];
  float* out = (float*)d_out;

  char* ws = (char*)d_ws;
  size_t off = 0;
  auto alloc = [&](size_t bytes) { char* p = ws + off; off += (bytes + 255) & ~255ull; return p; };
  ushort* xb   = (ushort*)alloc(16384ull * 1024 * 2);
  ushort* wqkv = (ushort*)alloc(3072ull * 1024 * 2);
  ushort* wpt  = (ushort*)alloc(1024ull * 1024 * 2);
  ushort* qws  = (ushort*)alloc(16384ull * 1024 * 2);
  ushort* kws  = (ushort*)alloc(16384ull * 1024 * 2);
  ushort* vws  = (ushort*)alloc(16384ull * 1024 * 2);
  ushort* vtws = (ushort*)alloc(16384ull * 1024 * 2);
  ushort* attb = xb;  // reuse: xb dead after k_gemm_qkv

  k_conv_x<<<16384, 256, 0, stream>>>(x, xb);
  k_conv_wqkv<<<12288, 256, 0, stream>>>(wq, wk, wv, wqkv);
  k_conv_wproj<<<4096, 256, 0, stream>>>(wp, wpt);
  k_gemm_qkv<<<768, 512, 0, stream>>>(xb, wqkv, qws, kws, vws);
  k_vtrans<<<dim3(32, 128), 256, 0, stream>>>(vws, vtws);
  k_attn<<<1024, 256, 0, stream>>>(qws, kws, vtws, attb);
  k_gemm_proj<<<256, 512, 0, stream>>>(attb, wpt, bp, out);
}

// Round 7
// 484.471 us; speedup vs baseline: 1.1252x; 1.1252x over previous
//
#include <hip/hip_runtime.h>
#include <stdint.h>

#define DEV static __device__ __forceinline__

typedef __attribute__((ext_vector_type(8))) short bf16x8;
typedef __attribute__((ext_vector_type(4))) float f32x4;

constexpr int Bc = 8, Tc = 2048, Cc = 1024, Hc = 16, Dc = 64;

DEV ushort f2bf(float f) {
  union { float f; uint32_t u; } x{f};
  uint32_t r = (x.u + 0x7FFFu + ((x.u >> 16) & 1u)) >> 16;
  return (ushort)r;
}

DEV uint32_t cvt_pk_bf16(float a, float b) {
  uint32_t r;
  asm("v_cvt_pk_bf16_f32 %0, %1, %2" : "=v"(r) : "v"(a), "v"(b));
  return r;
}

DEV float max3f(float a, float b, float c) {
  float r;
  asm("v_max3_f32 %0, %1, %2, %3" : "=v"(r) : "v"(a), "v"(b), "v"(c));
  return r;
}

DEV void gload16(const ushort* g, ushort* l) {
  __builtin_amdgcn_global_load_lds(
      (const __attribute__((address_space(1))) unsigned int*)g,
      (__attribute__((address_space(3))) unsigned int*)l, 16, 0, 0);
}

DEV f32x4 mfma16(bf16x8 a, bf16x8 b, f32x4 c) {
  return __builtin_amdgcn_mfma_f32_16x16x32_bf16(a, b, c, 0, 0, 0);
}

union B8 { bf16x8 v; uint4 u; };

// counted-vmcnt primitives
DEV void vm4() { asm volatile("s_waitcnt vmcnt(4)" ::: "memory"); }
DEV void vm0() { asm volatile("s_waitcnt vmcnt(0)" ::: "memory"); }
DEV void memfence() { asm volatile("" ::: "memory"); }
DEV void pbar() {
  __builtin_amdgcn_sched_barrier(0);
  __builtin_amdgcn_s_barrier();
  __builtin_amdgcn_sched_barrier(0);
}

// ---------------- converts ----------------
__global__ __launch_bounds__(256) void k_conv_x(const float* __restrict__ x, ushort* __restrict__ xb) {
  int i = blockIdx.x * 256 + threadIdx.x;
  float4 v = ((const float4*)x)[i];
  ushort4 o = make_ushort4(f2bf(v.x), f2bf(v.y), f2bf(v.z), f2bf(v.w));
  ((ushort4*)xb)[i] = o;
}

__global__ __launch_bounds__(256) void k_conv_wqkv(const float* __restrict__ wq, const float* __restrict__ wk,
                                                   const float* __restrict__ wv, ushort* __restrict__ wt) {
  int i = blockIdx.x * 256 + threadIdx.x;   // 0 .. 3072*1024-1
  int c = i & 1023;
  int n = i >> 10;
  int which = n >> 10;
  int rem = n & 1023;
  int h = rem >> 6, d = rem & 63;
  const float* src = which == 0 ? wq : (which == 1 ? wk : wv);
  float v = src[((size_t)h * 1024 + c) * 64 + d];
  // fold C^-0.5 = 1/32 AND log2(e) (for exp2-softmax) into wq
  if (which == 0) v *= 0.03125f * 1.44269504088896340736f;
  wt[i] = f2bf(v);
}

__global__ __launch_bounds__(256) void k_conv_wproj(const float* __restrict__ wp, ushort* __restrict__ wt) {
  int i = blockIdx.x * 256 + threadIdx.x;   // 0 .. 1024*1024-1
  int n = i >> 10, k = i & 1023;
  wt[i] = f2bf(wp[(size_t)k * 1024 + n]);
}

// ---------------- 256x256 8-wave counted-vmcnt GEMM mainloop (K=1024, BK=64) ----------------
DEV void gemm256_main(const ushort* __restrict__ A, const ushort* __restrict__ B,
                      int m0, int n0, int tid, ushort* ldsA, ushort* ldsB,
                      f32x4 (&acc)[8][4]) {
  const int lane = tid & 63;
  const int lr = lane & 15, lg = lane >> 4;
  const int wid = tid >> 6;
  const int wm = wid >> 2, wn = wid & 3;
  constexpr int NT = 16;

  auto stageA = [&](int q, int t) {
#pragma unroll
    for (int j = 0; j < 2; ++j) {
      int c = tid + q * 512 + j * 1024;
      int row = c >> 3;
      int col = 8 * ((c & 7) ^ (row & 7));
      gload16(&A[(size_t)(m0 + row) * 1024 + t * 64 + col], &ldsA[(t & 1) * 16384 + c * 8]);
    }
  };
  auto stageB = [&](int q, int t) {
#pragma unroll
    for (int j = 0; j < 2; ++j) {
      int c = q * 256 + (tid & 255) + ((tid >> 8) + 2 * j) * 512;
      int row = c >> 3;
      int col = 8 * ((c & 7) ^ (row & 7));
      gload16(&B[(size_t)(n0 + row) * 1024 + t * 64 + col], &ldsB[(t & 1) * 16384 + c * 8]);
    }
  };
  auto rdA = [&](bf16x8 (&af)[2][4], const ushort* bA, int mh) {
#pragma unroll
    for (int kc = 0; kc < 2; ++kc)
#pragma unroll
      for (int mf = 0; mf < 4; ++mf) {
        int row = wm * 128 + mh * 64 + mf * 16 + lr;
        af[kc][mf] = *(const bf16x8*)((const char*)bA + row * 128 + ((kc * 64 + lg * 16) ^ ((row & 7) << 4)));
      }
  };
  auto rdB = [&](bf16x8 (&bf)[2][2], const ushort* bB, int nh) {
#pragma unroll
    for (int kc = 0; kc < 2; ++kc)
#pragma unroll
      for (int nf = 0; nf < 2; ++nf) {
        int row = wn * 64 + nh * 32 + nf * 16 + lr;
        bf[kc][nf] = *(const bf16x8*)((const char*)bB + row * 128 + ((kc * 64 + lg * 16) ^ ((row & 7) << 4)));
      }
  };

  // prologue: tile 0, fence-separated quarter order [Aq0,Bq0 | Aq1,Bq1]
  stageA(0, 0); stageB(0, 0);
  memfence();
  stageA(1, 0); stageB(1, 0);
  vm4();
  pbar();

  for (int t = 0; t < NT; ++t) {
    const ushort* bA = ldsA + (t & 1) * 16384;
    const ushort* bB = ldsB + (t & 1) * 16384;
    const bool pf = (t + 1) < NT;
    bf16x8 af[2][4], bf0[2][2], bf1[2][2];
    // ---- P1: reads Aq0(t)+Bq0(t); issues Aq0,Bq0(t+1)
    if (pf) { stageA(0, t + 1); stageB(0, t + 1); }
    rdA(af, bA, 0);
    rdB(bf0, bB, 0);
    __builtin_amdgcn_s_setprio(1);
#pragma unroll
    for (int kc = 0; kc < 2; ++kc)
#pragma unroll
      for (int mf = 0; mf < 4; ++mf)
#pragma unroll
        for (int nf = 0; nf < 2; ++nf)
          acc[mf][nf] = mfma16(af[kc][mf], bf0[kc][nf], acc[mf][nf]);
    __builtin_amdgcn_s_setprio(0);
    if (pf) vm4(); else vm0();   // F1: {Aq1,Bq1}(t) landed
    pbar();
    // ---- P2: reads Bq1(t); issues Aq1(t+1)
    if (pf) stageA(1, t + 1);
    rdB(bf1, bB, 1);
    __builtin_amdgcn_s_setprio(1);
#pragma unroll
    for (int kc = 0; kc < 2; ++kc)
#pragma unroll
      for (int mf = 0; mf < 4; ++mf)
#pragma unroll
        for (int nf = 0; nf < 2; ++nf)
          acc[mf][2 + nf] = mfma16(af[kc][mf], bf1[kc][nf], acc[mf][2 + nf]);
    __builtin_amdgcn_s_setprio(0);
    // ---- P3: reads Aq1(t); issues Bq1(t+1)
    if (pf) stageB(1, t + 1);
    rdA(af, bA, 1);
    __builtin_amdgcn_s_setprio(1);
#pragma unroll
    for (int kc = 0; kc < 2; ++kc)
#pragma unroll
      for (int mf = 0; mf < 4; ++mf)
#pragma unroll
        for (int nf = 0; nf < 2; ++nf)
          acc[4 + mf][nf] = mfma16(af[kc][mf], bf0[kc][nf], acc[4 + mf][nf]);
    __builtin_amdgcn_s_setprio(0);
    // ---- P4 (no new ds_reads)
    __builtin_amdgcn_s_setprio(1);
#pragma unroll
    for (int kc = 0; kc < 2; ++kc)
#pragma unroll
      for (int mf = 0; mf < 4; ++mf)
#pragma unroll
        for (int nf = 0; nf < 2; ++nf)
          acc[4 + mf][2 + nf] = mfma16(af[kc][mf], bf1[kc][nf], acc[4 + mf][2 + nf]);
    __builtin_amdgcn_s_setprio(0);
    if (pf) vm4(); else vm0();   // F4: {Aq0,Bq0}(t+1) landed
    pbar();
  }
}

// ---------------- QKV projection GEMM (256^2); V written directly transposed ----------------
__global__ __launch_bounds__(512, 2) void k_gemm_qkv(const ushort* __restrict__ xb, const ushort* __restrict__ wt,
                                                     ushort* __restrict__ qws, ushort* __restrict__ kws,
                                                     ushort* __restrict__ vtws) {
  __shared__ __align__(16) ushort ldsA[2 * 16384];
  __shared__ __align__(16) ushort ldsB[2 * 16384];
  const int tid = threadIdx.x;
  const int orig = blockIdx.x;                 // 768 blocks
  const int wgid = (orig & 7) * 96 + (orig >> 3);  // bijective XCD swizzle (768 % 8 == 0)
  const int bn = wgid >> 6, bm = wgid & 63;    // consecutive wgid share B panel
  const int m0 = bm * 256, n0 = bn * 256;
  f32x4 acc[8][4];
  f32x4 z = {0.f, 0.f, 0.f, 0.f};
#pragma unroll
  for (int i = 0; i < 8; ++i)
#pragma unroll
    for (int j = 0; j < 4; ++j) acc[i][j] = z;
  gemm256_main(xb, wt, m0, n0, tid, ldsA, ldsB, acc);
  const int lane = tid & 63, wid = tid >> 6;
  const int lr = lane & 15, lg = lane >> 4;
  const int wm = wid >> 2, wn = wid & 3;
#pragma unroll
  for (int a = 0; a < 8; ++a)
#pragma unroll
    for (int nf = 0; nf < 4; ++nf) {
      const int mbase = m0 + wm * 128 + (a >> 2) * 64 + (a & 3) * 16 + lg * 4;
      const int n = n0 + wn * 64 + nf * 16 + lr;
      const int which = n >> 10, rem = n & 1023;
      const int h = rem >> 6, d = rem & 63;
      const int b = mbase >> 11, t = mbase & 2047;
      if (which == 2) {
        // V^T: (bh, d, t) with 4 consecutive t -> one 8B store
        ushort4 vv = make_ushort4(f2bf(acc[a][nf][0]), f2bf(acc[a][nf][1]),
                                  f2bf(acc[a][nf][2]), f2bf(acc[a][nf][3]));
        *(ushort4*)&vtws[((size_t)(b * Hc + h) * 64 + d) * Tc + t] = vv;
      } else {
        ushort* dst = which == 0 ? qws : kws;
#pragma unroll
        for (int r = 0; r < 4; ++r)
          dst[((size_t)(b * Hc + h) * Tc + (t + r)) * 64 + d] = f2bf(acc[a][nf][r]);
      }
    }
}

// ---------------- output projection GEMM (256^2, +bias, fp32 out) ----------------
__global__ __launch_bounds__(512, 2) void k_gemm_proj(const ushort* __restrict__ attb, const ushort* __restrict__ wt,
                                                      const float* __restrict__ bias, float* __restrict__ out) {
  __shared__ __align__(16) ushort ldsA[2 * 16384];
  __shared__ __align__(16) ushort ldsB[2 * 16384];
  const int tid = threadIdx.x;
  const int orig = blockIdx.x;                 // 256 blocks
  const int wgid = (orig & 7) * 32 + (orig >> 3);  // bijective XCD swizzle (256 % 8 == 0)
  const int bn = wgid >> 6, bm = wgid & 63;
  const int m0 = bm * 256, n0 = bn * 256;
  f32x4 acc[8][4];
  f32x4 z = {0.f, 0.f, 0.f, 0.f};
#pragma unroll
  for (int i = 0; i < 8; ++i)
#pragma unroll
    for (int j = 0; j < 4; ++j) acc[i][j] = z;
  gemm256_main(attb, wt, m0, n0, tid, ldsA, ldsB, acc);
  const int lane = tid & 63, wid = tid >> 6;
  const int lr = lane & 15, lg = lane >> 4;
  const int wm = wid >> 2, wn = wid & 3;
#pragma unroll
  for (int a = 0; a < 8; ++a)
#pragma unroll
    for (int nf = 0; nf < 4; ++nf)
#pragma unroll
      for (int r = 0; r < 4; ++r) {
        int m = m0 + wm * 128 + (a >> 2) * 64 + (a & 3) * 16 + lg * 4 + r;
        int n = n0 + wn * 64 + nf * 16 + lr;
        out[(size_t)m * 1024 + n] = acc[a][nf][r] + bias[n];
      }
}

// ---------------- flash attention (causal) ----------------
// 512 threads / 8 waves / QBLK=256 rows, KVBLK=128, double-buffered 64 KB LDS.
// Paired q-blocks (pr, 7-pr): every block = exactly 18 KV tiles. 1 block/CU
// (VGPR-capped); resident 32 blocks/XCD -> 8 bh live = 4 MB KV = L2-fit.
// Swapped QK^T; in-register softmax/P; l via MFMA ones-column; staging via
// global_load_lds with pre-swizzled global source (linear LDS dest, swizzled read).
DEV int swzK(int row, int bcol) { return row * 128 + (bcol ^ ((row & 7) << 4)); }  // 128B pitch
DEV int swzV(int row, int bcol) { return row * 256 + (bcol ^ ((row & 7) << 4)); }  // 256B pitch

__global__ __launch_bounds__(512) void k_attn(const ushort* __restrict__ qws, const ushort* __restrict__ kws,
                                              const ushort* __restrict__ vtws, ushort* __restrict__ att) {
  const int id = blockIdx.x;                 // 512 blocks
  const int xcd = id & 7, slot = id >> 3;    // 64 slots per XCD
  const int bh = (xcd << 4) + (slot >> 2);   // 16 bh per XCD; resident slots span 8 bh
  const int pr = slot & 3;                   // pair index 0..3
  const int tid = threadIdx.x, lane = tid & 63, wid = tid >> 6;  // wid 0..7
  const int lr = lane & 15, lg = lane >> 4;

  __shared__ __align__(16) ushort lds_k[2 * 128 * 64];  // K: 128 s-rows x 64 d (128B pitch)
  __shared__ __align__(16) ushort lds_v[2 * 64 * 128];  // V^T: 64 d-rows x 128 s (256B pitch)

  const ushort* qbase = qws + (size_t)bh * Tc * 64;
  const ushort* kbase = kws + (size_t)bh * Tc * 64;
  const ushort* vtbase = vtws + (size_t)bh * 64 * Tc;
  const int b = bh >> 4, h = bh & 15;
  const f32x4 z = {0.f, 0.f, 0.f, 0.f};

  // staging coords (pre-swizzled source columns; LDS dest stays linear)
  int rowK[2], colK[2], rowV[2], colV[2];
#pragma unroll
  for (int r = 0; r < 2; ++r) {
    int c = r * 512 + tid;
    rowK[r] = c >> 3;  colK[r] = 8 * ((c & 7) ^ (rowK[r] & 7));
    rowV[r] = c >> 4;  colV[r] = 8 * ((c & 15) ^ (rowV[r] & 7));
  }

  // ones B-fragment (col n=0 only) for l = P . ones via MFMA
  B8 onesf;
  {
    uint32_t pp = lr == 0 ? 0x3F803F80u : 0u;
    onesf.u = make_uint4(pp, pp, pp, pp);
  }

  for (int pass = 0; pass < 2; ++pass) {
    const int qb = pass == 0 ? pr : 7 - pr;
    const int q0 = qb * 256;
    const int ntiles = 2 * qb + 2;          // KVBLK=128, QBLK=256
    const int qrow = q0 + wid * 32;
    const int qgmax = qrow + 31;

    // Q fragments (B-operand: lane (lg,lr) holds Q[qf*16+lr][kc*32+lg*8 ..+7])
    bf16x8 qa[2][2];
#pragma unroll
    for (int qf = 0; qf < 2; ++qf)
#pragma unroll
      for (int kc = 0; kc < 2; ++kc)
        qa[qf][kc] = *(const bf16x8*)&qbase[(size_t)(qrow + qf * 16 + lr) * 64 + kc * 32 + lg * 8];

    f32x4 o[2][4];
    f32x4 lac[2];
    float m_[2];
#pragma unroll
    for (int qf = 0; qf < 2; ++qf) {
#pragma unroll
      for (int df = 0; df < 4; ++df) o[qf][df] = z;
      lac[qf] = z;
      m_[qf] = -1e30f;
    }

    __syncthreads();  // previous pass's readers done before restaging buf 0

    // prologue: stage tile 0 into buffer 0 (async, drains at first loop barrier)
#pragma unroll
    for (int r = 0; r < 2; ++r) {
      gload16(&kbase[(size_t)rowK[r] * 64 + colK[r]], &lds_k[(r * 512 + tid) * 8]);
      gload16(&vtbase[(size_t)rowV[r] * Tc + colV[r]], &lds_v[(r * 512 + tid) * 8]);
    }

    for (int it = 0; it < ntiles; ++it) {
      __syncthreads();  // drains this tile's loads; makes them visible to all waves
      const ushort* ldsK = lds_k + (it & 1) * 8192;
      const ushort* ldsV = lds_v + (it & 1) * 8192;
      if (it + 1 < ntiles) {  // issue next tile's loads; land during this tile's compute
        const int s0n = (it + 1) * 128;
        ushort* dK = lds_k + ((it + 1) & 1) * 8192;
        ushort* dV = lds_v + ((it + 1) & 1) * 8192;
#pragma unroll
        for (int r = 0; r < 2; ++r) {
          gload16(&kbase[(size_t)(s0n + rowK[r]) * 64 + colK[r]], &dK[(r * 512 + tid) * 8]);
          gload16(&vtbase[(size_t)rowV[r] * Tc + s0n + colV[r]], &dV[(r * 512 + tid) * 8]);
        }
      }

      const int s0 = it * 128;
      if (s0 > qgmax) continue;  // fully masked for this wave (still staged for others)
      const int nlive = min(8, ((qgmax - s0) >> 4) + 1);  // live 16-row s-strips
      const bool maskNeeded = (s0 + 127 > qrow);

      // ---- QK^T swapped: lane (lg,lr): s[sf][qf][r] = S[s0+sf*16+lg*4+r][qrow+qf*16+lr]
      f32x4 s[8][2];
#pragma unroll
      for (int sf = 0; sf < 8; ++sf)
#pragma unroll
        for (int qf = 0; qf < 2; ++qf) s[sf][qf] = z;
#pragma unroll
      for (int kc = 0; kc < 2; ++kc) {
        bf16x8 kf[8];
#pragma unroll
        for (int sf = 0; sf < 8; ++sf)
          if (sf < nlive)
            kf[sf] = *(const bf16x8*)((const char*)ldsK + swzK(sf * 16 + lr, kc * 64 + lg * 16));
        __builtin_amdgcn_s_setprio(1);
#pragma unroll
        for (int sf = 0; sf < 8; ++sf)
          if (sf < nlive)
#pragma unroll
            for (int qf = 0; qf < 2; ++qf)
              s[sf][qf] = mfma16(kf[sf], qa[qf][kc], s[sf][qf]);
        __builtin_amdgcn_s_setprio(0);
      }

      if (maskNeeded) {  // causal masking (also nukes dead strips: s=0 -> -1e30)
#pragma unroll
        for (int sf = 0; sf < 8; ++sf)
#pragma unroll
          for (int qf = 0; qf < 2; ++qf)
#pragma unroll
            for (int r = 0; r < 4; ++r) {
              int sg = s0 + sf * 16 + lg * 4 + r;
              int qg = qrow + qf * 16 + lr;
              if (sg > qg) s[sf][qf][r] = -1e30f;
            }
      }

      // ---- online softmax (base-2 units), defer-max rescale
      float sc[2];
      bool defer[2];
#pragma unroll
      for (int qf = 0; qf < 2; ++qf) {
        float rs[8];
#pragma unroll
        for (int sf = 0; sf < 8; ++sf)
          rs[sf] = fmaxf(max3f(s[sf][qf][0], s[sf][qf][1], s[sf][qf][2]), s[sf][qf][3]);
        float t = max3f(max3f(rs[0], rs[1], rs[2]), max3f(rs[3], rs[4], rs[5]), fmaxf(rs[6], rs[7]));
        t = fmaxf(t, __shfl_xor(t, 16));
        t = fmaxf(t, __shfl_xor(t, 32));
        defer[qf] = __all(t <= m_[qf] + 11.54f) != 0;  // ~e^8 headroom
        float mnew = defer[qf] ? m_[qf] : fmaxf(m_[qf], t);
        sc[qf] = defer[qf] ? 1.f : exp2f(m_[qf] - mnew);
        m_[qf] = mnew;
#pragma unroll
        for (int sf = 0; sf < 8; ++sf)
#pragma unroll
          for (int r = 0; r < 4; ++r)
            s[sf][qf][r] = exp2f(s[sf][qf][r] - mnew);
      }
#pragma unroll
      for (int qf = 0; qf < 2; ++qf)
        if (!defer[qf]) {
#pragma unroll
          for (int r = 0; r < 4; ++r) {
            float scR = __shfl(sc[qf], ((lane >> 4) << 2) + r);
#pragma unroll
            for (int df = 0; df < 4; ++df) o[qf][df][r] *= scR;
            lac[qf][r] *= scR;
          }
        }

      // ---- pack P to bf16 in-register
      uint32_t pk_[8][2][2];
#pragma unroll
      for (int sf = 0; sf < 8; ++sf)
#pragma unroll
        for (int qf = 0; qf < 2; ++qf) {
          pk_[sf][qf][0] = cvt_pk_bf16(s[sf][qf][0], s[sf][qf][1]);
          pk_[sf][qf][1] = cvt_pk_bf16(s[sf][qf][2], s[sf][qf][3]);
        }

      // ---- PV with permuted k-slots; l accumulated on the matrix pipe (ones column)
#pragma unroll
      for (int kc = 0; kc < 4; ++kc) {
        B8 vf[4];
#pragma unroll
        for (int df = 0; df < 4; ++df) {
          uint2 lo = *(const uint2*)((const char*)ldsV + swzV(df * 16 + lr, kc * 64 + lg * 8));
          uint2 hi = *(const uint2*)((const char*)ldsV + swzV(df * 16 + lr, kc * 64 + 32 + lg * 8));
          vf[df].u = make_uint4(lo.x, lo.y, hi.x, hi.y);
        }
        B8 pf[2];
#pragma unroll
        for (int qf = 0; qf < 2; ++qf)
          pf[qf].u = make_uint4(pk_[2 * kc][qf][0], pk_[2 * kc][qf][1],
                                pk_[2 * kc + 1][qf][0], pk_[2 * kc + 1][qf][1]);
        __builtin_amdgcn_s_setprio(1);
#pragma unroll
        for (int qf = 0; qf < 2; ++qf) {
#pragma unroll
          for (int df = 0; df < 4; ++df)
            o[qf][df] = mfma16(pf[qf].v, vf[df].v, o[qf][df]);
          lac[qf] = mfma16(pf[qf].v, onesf.v, lac[qf]);
        }
        __builtin_amdgcn_s_setprio(0);
      }
    }

    // epilogue: l lives in col 0 (lane lg*16), rows lg*4+r — broadcast and store
#pragma unroll
    for (int qf = 0; qf < 2; ++qf)
#pragma unroll
      for (int r = 0; r < 4; ++r) {
        float lR = __shfl(lac[qf][r], lg << 4);
        float inv = 1.f / lR;
        int qg = qrow + qf * 16 + lg * 4 + r;
#pragma unroll
        for (int df = 0; df < 4; ++df) {
          int d = df * 16 + lr;
          att[(size_t)(b * Tc + qg) * 1024 + h * 64 + d] = f2bf(o[qf][df][r] * inv);
        }
      }
  }
}

extern "C" void kernel_launch(void* const* d_in, const int* in_sizes, int n_in,
                              void* d_out, int out_size, void* d_ws, size_t ws_size,
                              hipStream_t stream) {
  const float* x  = (const float*)d_in[0];
  const float* wq = (const float*)d_in[1];
  const float* wk = (const float*)d_in[2];
  const float* wv = (const float*)d_in[3];
  const float* wp = (const float*)d_in[4];
  const float* bp = (const float*)d_in[5];
  float* out = (float*)d_out;

  char* ws = (char*)d_ws;
  size_t off = 0;
  auto alloc = [&](size_t bytes) { char* p = ws + off; off += (bytes + 255) & ~255ull; return p; };
  ushort* xb   = (ushort*)alloc(16384ull * 1024 * 2);
  ushort* wqkv = (ushort*)alloc(3072ull * 1024 * 2);
  ushort* wpt  = (ushort*)alloc(1024ull * 1024 * 2);
  ushort* qws  = (ushort*)alloc(16384ull * 1024 * 2);
  ushort* kws  = (ushort*)alloc(16384ull * 1024 * 2);
  ushort* vtws = (ushort*)alloc(16384ull * 1024 * 2);
  ushort* attb = xb;  // reuse: xb dead after k_gemm_qkv

  k_conv_x<<<16384, 256, 0, stream>>>(x, xb);
  k_conv_wqkv<<<12288, 256, 0, stream>>>(wq, wk, wv, wqkv);
  k_conv_wproj<<<4096, 256, 0, stream>>>(wp, wpt);
  k_gemm_qkv<<<768, 512, 0, stream>>>(xb, wqkv, qws, kws, vtws);
  k_attn<<<512, 512, 0, stream>>>(qws, kws, vtws, attb);
  k_gemm_proj<<<256, 512, 0, stream>>>(attb, wpt, bp, out);
}